// Round 6
// baseline (188.402 us; speedup 1.0000x reference)
//
#include <hip/hip_runtime.h>

// DICE multi-class loss (fused single-kernel).
//   output: [B=16, C=8, H=512, W=512] fp32
//   mask:   [B=16, H=512, W=512] int32 (labels 0..7)
// loss = 1 - sum_{b,c} dice(b,c) / (B*B),  dice = 2*(num+eps)/(den1+den2+eps)
//
// R4 lesson: don't drop below ~4 blocks/CU (latency-bound at 2/CU).
// R5 win: DPP VALU wave-reduce instead of ds_bpermute shuffles (33.9->30.7us).
// R6: last-block-done fusion (rocPRIM pattern) removes the dice_final launch
//     and its latency-bound single-block read; BPB 128->64 halves partials.

#define BB 16
#define CC 8
#define HWPIX (512 * 512)
#define HW4 (HWPIX / 4)      // 65536 float4-quads per plane
#define BPB 64               // partial-blocks per batch image
#define QPB (HW4 / BPB)      // 1024 quads per block -> 4 iters/thread
#define NBLOCKS (BB * BPB)   // 1024 blocks = 4/CU co-resident
#define CNT_OFF (3 * BB * CC * BPB)   // float index of ticket counter in ws

typedef float f32x4 __attribute__((ext_vector_type(4)));
typedef int i32x4 __attribute__((ext_vector_type(4)));

// ---- DPP wave64 sum (VALU pipe only, no DS ops); total lands in lane 63 ----
template <int CTRL>
__device__ __forceinline__ float dpp_add(float x) {
    int yi = __builtin_amdgcn_update_dpp(0, __float_as_int(x), CTRL, 0xf, 0xf, true);
    return x + __int_as_float(yi);
}
__device__ __forceinline__ float wave_sum63(float x) {
    x = dpp_add<0x111>(x);   // row_shr:1
    x = dpp_add<0x112>(x);   // row_shr:2
    x = dpp_add<0x114>(x);   // row_shr:4
    x = dpp_add<0x118>(x);   // row_shr:8
    x = dpp_add<0x142>(x);   // row_bcast:15
    x = dpp_add<0x143>(x);   // row_bcast:31
    return x;
}

__global__ __launch_bounds__(256) void dice_fused(const float* __restrict__ out,
                                                  const int* __restrict__ mask,
                                                  float* __restrict__ ws,
                                                  int* __restrict__ cnt,
                                                  float* __restrict__ loss) {
    const int b = blockIdx.x / BPB;
    const int blk = blockIdx.x % BPB;
    const f32x4* __restrict__ ov = (const f32x4*)(out + (size_t)b * CC * HWPIX);
    const i32x4* __restrict__ mv = (const i32x4*)(mask + (size_t)b * HWPIX);

    float num[CC], d1[CC], d2[CC];
#pragma unroll
    for (int c = 0; c < CC; ++c) { num[c] = 0.f; d1[c] = 0.f; d2[c] = 0.f; }

    const int q0 = blk * QPB;
#pragma unroll 2
    for (int q = q0 + threadIdx.x; q < q0 + QPB; q += 256) {
        const i32x4 m = __builtin_nontemporal_load(&mv[q]);
        f32x4 v[CC];
#pragma unroll
        for (int c = 0; c < CC; ++c) v[c] = __builtin_nontemporal_load(&ov[c * HW4 + q]);
#pragma unroll
        for (int c = 0; c < CC; ++c) {
            d1[c] += v[c].x * v[c].x + v[c].y * v[c].y + v[c].z * v[c].z + v[c].w * v[c].w;
            float hx = (m.x == c) ? 1.f : 0.f;
            float hy = (m.y == c) ? 1.f : 0.f;
            float hz = (m.z == c) ? 1.f : 0.f;
            float hw = (m.w == c) ? 1.f : 0.f;
            num[c] += hx * v[c].x + hy * v[c].y + hz * v[c].z + hw * v[c].w;
            d2[c] += hx + hy + hz + hw;
        }
    }

    const int lane = threadIdx.x & 63;
    const int wid = threadIdx.x >> 6;
    __shared__ float red[4][24];
#pragma unroll
    for (int c = 0; c < CC; ++c) {
        float a0 = wave_sum63(num[c]);
        float a1 = wave_sum63(d1[c]);
        float a2 = wave_sum63(d2[c]);
        if (lane == 63) {
            red[wid][0 * 8 + c] = a0;
            red[wid][1 * 8 + c] = a1;
            red[wid][2 * 8 + c] = a2;
        }
    }
    __syncthreads();
    if (threadIdx.x < 24) {
        const int k = threadIdx.x;       // k = qy*8 + c
        const int qy = k >> 3;
        const int c = k & 7;
        float s = red[0][k] + red[1][k] + red[2][k] + red[3][k];
        ws[((qy * BB + b) * CC + c) * BPB + blk] = s;
    }

    // ---- last-block-done final reduction (rocPRIM deviceReduce pattern) ----
    __syncthreads();                 // implies vmcnt(0): partial stores issued & done
    __threadfence();                 // release: make partials device-visible
    __shared__ int tk;
    if (threadIdx.x == 0) tk = atomicAdd(cnt, 1);
    __syncthreads();
    if (tk != NBLOCKS - 1) return;
    __threadfence();                 // acquire: invalidate stale L1/L2 lines

    const int t = threadIdx.x;
    const int g = t >> 1;            // (b,c) pair 0..127
    const int sub = t & 1;           // half of the 64 partials
    const int fb = g >> 3;
    const int fc = g & 7;

    float acc[3] = {0.f, 0.f, 0.f};
#pragma unroll
    for (int qy = 0; qy < 3; ++qy) {
        const f32x4* p = (const f32x4*)(ws + ((qy * BB + fb) * CC + fc) * BPB) + sub * 8;
#pragma unroll
        for (int i = 0; i < 8; ++i) {
            f32x4 v = p[i];
            acc[qy] += v.x + v.y + v.z + v.w;
        }
    }
#pragma unroll
    for (int qy = 0; qy < 3; ++qy) acc[qy] += __shfl_down(acc[qy], 1, 2);

    __shared__ float smv[128];
    __shared__ float sm2[2];
    if (sub == 0) {
        const float eps = 1e-7f;
        smv[g] = 2.f * (acc[0] + eps) / (acc[1] + acc[2] + eps);
    }
    __syncthreads();
    if (t < 128) {
        float x = wave_sum63(smv[t]);
        if ((t & 63) == 63) sm2[t >> 6] = x;
    }
    __syncthreads();
    if (t == 0) loss[0] = 1.f - (sm2[0] + sm2[1]) / ((float)BB * (float)BB);
}

extern "C" void kernel_launch(void* const* d_in, const int* in_sizes, int n_in,
                              void* d_out, int out_size, void* d_ws, size_t ws_size,
                              hipStream_t stream) {
    const float* out_probs = (const float*)d_in[0];
    const int* mask = (const int*)d_in[1];
    float* ws = (float*)d_ws;                 // 3*16*8*64 floats = 96 KiB + 4B counter
    int* cnt = (int*)(ws + CNT_OFF);
    float* loss = (float*)d_out;

    // zero the ticket counter each call (graph-capture-safe, deterministic)
    hipMemsetAsync(cnt, 0, sizeof(int), stream);
    dice_fused<<<NBLOCKS, 256, 0, stream>>>(out_probs, mask, ws, cnt, loss);
}

// Round 7
// 32.794 us; speedup vs baseline: 5.7450x; 5.7450x over previous
//
#include <hip/hip_runtime.h>

// DICE multi-class loss.
//   output: [B=16, C=8, H=512, W=512] fp32
//   mask:   [B=16, H=512, W=512] int32 (labels 0..7)
// loss = 1 - sum_{b,c} dice(b,c) / (B*B),  dice = 2*(num+eps)/(den1+den2+eps)
//
// R4 lesson: keep 32 waves/CU (8 waves/CU is latency-bound).
// R5 win: DPP VALU wave-reduce, no DS-pipe shuffles (33.9 -> 30.7us).
// R6 lesson: NO per-block device-scope fences (threadfence = per-XCD L2
//   flush -> 6x regression). Also: input (144MiB) fits L3; FETCH showed 76MB
//   -> half was L3-resident DESPITE nontemporal loads evicting it. R7 drops
//   the NT hints to keep inputs Infinity-Cache-resident across graph replays.

#define BB 16
#define CC 8
#define HWPIX (512 * 512)
#define HW4 (HWPIX / 4)      // 65536 float4-quads per plane
#define BPB 64               // partial-blocks per batch image
#define QPB (HW4 / BPB)      // 1024 quads per block -> 2 iters @ 512 thr
#define NBLOCKS (BB * BPB)   // 1024 blocks x 8 waves = 4 blocks/CU, 32 waves/CU

typedef float f32x4 __attribute__((ext_vector_type(4)));
typedef int i32x4 __attribute__((ext_vector_type(4)));

// ---- DPP wave64 sum (VALU pipe only, no DS ops); total lands in lane 63 ----
template <int CTRL>
__device__ __forceinline__ float dpp_add(float x) {
    int yi = __builtin_amdgcn_update_dpp(0, __float_as_int(x), CTRL, 0xf, 0xf, true);
    return x + __int_as_float(yi);
}
__device__ __forceinline__ float wave_sum63(float x) {
    x = dpp_add<0x111>(x);   // row_shr:1
    x = dpp_add<0x112>(x);   // row_shr:2
    x = dpp_add<0x114>(x);   // row_shr:4
    x = dpp_add<0x118>(x);   // row_shr:8
    x = dpp_add<0x142>(x);   // row_bcast:15
    x = dpp_add<0x143>(x);   // row_bcast:31
    return x;
}

__global__ __launch_bounds__(512) void dice_partial(const float* __restrict__ out,
                                                    const int* __restrict__ mask,
                                                    float* __restrict__ ws) {
    const int b = blockIdx.x / BPB;
    const int blk = blockIdx.x % BPB;
    const f32x4* __restrict__ ov = (const f32x4*)(out + (size_t)b * CC * HWPIX);
    const i32x4* __restrict__ mv = (const i32x4*)(mask + (size_t)b * HWPIX);

    float num[CC], d1[CC], d2[CC];
#pragma unroll
    for (int c = 0; c < CC; ++c) { num[c] = 0.f; d1[c] = 0.f; d2[c] = 0.f; }

    const int q0 = blk * QPB;
#pragma unroll 2
    for (int q = q0 + threadIdx.x; q < q0 + QPB; q += 512) {
        const i32x4 m = mv[q];                 // plain loads: keep L3-resident
        f32x4 v[CC];
#pragma unroll
        for (int c = 0; c < CC; ++c) v[c] = ov[c * HW4 + q];
#pragma unroll
        for (int c = 0; c < CC; ++c) {
            d1[c] += v[c].x * v[c].x + v[c].y * v[c].y + v[c].z * v[c].z + v[c].w * v[c].w;
            float hx = (m.x == c) ? 1.f : 0.f;
            float hy = (m.y == c) ? 1.f : 0.f;
            float hz = (m.z == c) ? 1.f : 0.f;
            float hw = (m.w == c) ? 1.f : 0.f;
            num[c] += hx * v[c].x + hy * v[c].y + hz * v[c].z + hw * v[c].w;
            d2[c] += hx + hy + hz + hw;
        }
    }

    const int lane = threadIdx.x & 63;
    const int wid = threadIdx.x >> 6;          // 0..7
    __shared__ float red[8][24];
#pragma unroll
    for (int c = 0; c < CC; ++c) {
        float a0 = wave_sum63(num[c]);
        float a1 = wave_sum63(d1[c]);
        float a2 = wave_sum63(d2[c]);
        if (lane == 63) {
            red[wid][0 * 8 + c] = a0;
            red[wid][1 * 8 + c] = a1;
            red[wid][2 * 8 + c] = a2;
        }
    }
    __syncthreads();
    if (threadIdx.x < 24) {
        const int k = threadIdx.x;             // k = qy*8 + c
        const int qy = k >> 3;
        const int c = k & 7;
        float s = 0.f;
#pragma unroll
        for (int w = 0; w < 8; ++w) s += red[w][k];
        // partial layout: ws[((qy*BB + b)*CC + c)*BPB + blk]
        ws[((qy * BB + b) * CC + c) * BPB + blk] = s;
    }
}

// 1024 threads: 8 threads per (b,c) pair; each reads 2 f32x4 per quantity.
__global__ __launch_bounds__(1024) void dice_final(const float* __restrict__ ws,
                                                   float* __restrict__ out) {
    const int t = threadIdx.x;
    const int g = t >> 3;        // (b,c) group 0..127
    const int sub = t & 7;
    const int b = g >> 3;
    const int c = g & 7;

    float acc[3] = {0.f, 0.f, 0.f};   // num, d1, d2
#pragma unroll
    for (int qy = 0; qy < 3; ++qy) {
        const f32x4* p = (const f32x4*)(ws + ((qy * BB + b) * CC + c) * BPB);
#pragma unroll
        for (int i = 0; i < BPB / (8 * 4); ++i) {   // 2 f32x4 per thread
            f32x4 v = p[sub + i * 8];
            acc[qy] += v.x + v.y + v.z + v.w;
        }
    }
#pragma unroll
    for (int qy = 0; qy < 3; ++qy) {
#pragma unroll
        for (int o = 4; o > 0; o >>= 1) acc[qy] += __shfl_down(acc[qy], o, 8);
    }

    __shared__ float sm[128];
    __shared__ float sm2[2];
    if (sub == 0) {
        const float eps = 1e-7f;
        sm[g] = 2.f * (acc[0] + eps) / (acc[1] + acc[2] + eps);
    }
    __syncthreads();
    if (t < 128) {
        float x = wave_sum63(sm[t]);
        if ((t & 63) == 63) sm2[t >> 6] = x;
    }
    __syncthreads();
    if (t == 0) out[0] = 1.f - (sm2[0] + sm2[1]) / ((float)BB * (float)BB);
}

extern "C" void kernel_launch(void* const* d_in, const int* in_sizes, int n_in,
                              void* d_out, int out_size, void* d_ws, size_t ws_size,
                              hipStream_t stream) {
    const float* out_probs = (const float*)d_in[0];
    const int* mask = (const int*)d_in[1];
    float* ws = (float*)d_ws;    // 3*16*8*64 floats = 96 KiB
    float* loss = (float*)d_out;

    dice_partial<<<NBLOCKS, 512, 0, stream>>>(out_probs, mask, ws);
    dice_final<<<1, 1024, 0, stream>>>(ws, loss);
}

// Round 8
// 32.305 us; speedup vs baseline: 5.8319x; 1.0151x over previous
//
#include <hip/hip_runtime.h>

// DICE multi-class loss.
//   output: [B=16, C=8, H=512, W=512] fp32
//   mask:   [B=16, H=512, W=512] int32 (labels 0..7)
// loss = 1 - sum_{b,c} dice(b,c) / (B*B),  dice = 2*(num+eps)/(den1+den2+eps)
//
// R4: keep 32 waves/CU (8 waves/CU latency-bound).
// R5 win: DPP VALU wave-reduce, no DS-pipe shuffles (33.9 -> 30.7us).
// R6: NO per-block device-scope fences (per-XCD L2 flush -> 6x). FETCH=74MB
//     showed half the input L3-resident even with NT loads.
// R7 mistake: changed 3 vars at once (regressed). R8 = exact R5 minus NT
//     loads only: test whether plain loads keep the 144MiB input
//     Infinity-Cache-resident across graph replays.

#define BB 16
#define CC 8
#define HWPIX (512 * 512)
#define HW4 (HWPIX / 4)      // 65536 float4-quads per plane
#define BPB 128              // partial-blocks per batch image
#define QPB (HW4 / BPB)      // 512 quads per block -> 2 iters/thread
#define NBLOCKS (BB * BPB)   // 2048 blocks = 8/CU, 32 waves/CU

typedef float f32x4 __attribute__((ext_vector_type(4)));
typedef int i32x4 __attribute__((ext_vector_type(4)));

// ---- DPP wave64 sum (VALU pipe only, no DS ops); total lands in lane 63 ----
template <int CTRL>
__device__ __forceinline__ float dpp_add(float x) {
    int yi = __builtin_amdgcn_update_dpp(0, __float_as_int(x), CTRL, 0xf, 0xf, true);
    return x + __int_as_float(yi);
}
__device__ __forceinline__ float wave_sum63(float x) {
    x = dpp_add<0x111>(x);   // row_shr:1
    x = dpp_add<0x112>(x);   // row_shr:2
    x = dpp_add<0x114>(x);   // row_shr:4
    x = dpp_add<0x118>(x);   // row_shr:8
    x = dpp_add<0x142>(x);   // row_bcast:15
    x = dpp_add<0x143>(x);   // row_bcast:31
    return x;
}

__global__ __launch_bounds__(256) void dice_partial(const float* __restrict__ out,
                                                    const int* __restrict__ mask,
                                                    float* __restrict__ ws) {
    const int b = blockIdx.x / BPB;
    const int blk = blockIdx.x % BPB;
    const f32x4* __restrict__ ov = (const f32x4*)(out + (size_t)b * CC * HWPIX);
    const i32x4* __restrict__ mv = (const i32x4*)(mask + (size_t)b * HWPIX);

    float num[CC], d1[CC], d2[CC];
#pragma unroll
    for (int c = 0; c < CC; ++c) { num[c] = 0.f; d1[c] = 0.f; d2[c] = 0.f; }

    const int q0 = blk * QPB;
    for (int q = q0 + threadIdx.x; q < q0 + QPB; q += 256) {
        const i32x4 m = mv[q];                  // plain loads (R8: NT removed)
        f32x4 v[CC];
#pragma unroll
        for (int c = 0; c < CC; ++c) v[c] = ov[c * HW4 + q];
#pragma unroll
        for (int c = 0; c < CC; ++c) {
            d1[c] += v[c].x * v[c].x + v[c].y * v[c].y + v[c].z * v[c].z + v[c].w * v[c].w;
            float hx = (m.x == c) ? 1.f : 0.f;
            float hy = (m.y == c) ? 1.f : 0.f;
            float hz = (m.z == c) ? 1.f : 0.f;
            float hw = (m.w == c) ? 1.f : 0.f;
            num[c] += hx * v[c].x + hy * v[c].y + hz * v[c].z + hw * v[c].w;
            d2[c] += hx + hy + hz + hw;
        }
    }

    const int lane = threadIdx.x & 63;
    const int wid = threadIdx.x >> 6;
    __shared__ float red[4][24];
#pragma unroll
    for (int c = 0; c < CC; ++c) {
        float a0 = wave_sum63(num[c]);
        float a1 = wave_sum63(d1[c]);
        float a2 = wave_sum63(d2[c]);
        if (lane == 63) {
            red[wid][0 * 8 + c] = a0;
            red[wid][1 * 8 + c] = a1;
            red[wid][2 * 8 + c] = a2;
        }
    }
    __syncthreads();
    if (threadIdx.x < 24) {
        const int k = threadIdx.x;       // k = qy*8 + c
        const int qy = k >> 3;
        const int c = k & 7;
        float s = red[0][k] + red[1][k] + red[2][k] + red[3][k];
        // partial layout: ws[((qy*BB + b)*CC + c)*BPB + blk]
        ws[((qy * BB + b) * CC + c) * BPB + blk] = s;
    }
}

// 1024 threads: 8 threads per (b,c) pair, 4 f32x4 loads each.
__global__ __launch_bounds__(1024) void dice_final(const float* __restrict__ ws,
                                                   float* __restrict__ out) {
    const int t = threadIdx.x;
    const int g = t >> 3;        // (b,c) group 0..127
    const int sub = t & 7;
    const int b = g >> 3;
    const int c = g & 7;

    float acc[3] = {0.f, 0.f, 0.f};   // num, d1, d2
#pragma unroll
    for (int qy = 0; qy < 3; ++qy) {
        const f32x4* p = (const f32x4*)(ws + ((qy * BB + b) * CC + c) * BPB);
#pragma unroll
        for (int i = 0; i < BPB / (8 * 4); ++i) {   // 4 f32x4 per thread
            f32x4 v = p[sub + i * 8];
            acc[qy] += v.x + v.y + v.z + v.w;
        }
    }
#pragma unroll
    for (int qy = 0; qy < 3; ++qy) {
#pragma unroll
        for (int o = 4; o > 0; o >>= 1) acc[qy] += __shfl_down(acc[qy], o, 8);
    }

    __shared__ float sm[128];
    __shared__ float sm2[2];
    if (sub == 0) {
        const float eps = 1e-7f;
        sm[g] = 2.f * (acc[0] + eps) / (acc[1] + acc[2] + eps);
    }
    __syncthreads();
    if (t < 128) {
        float x = wave_sum63(sm[t]);
        if ((t & 63) == 63) sm2[t >> 6] = x;
    }
    __syncthreads();
    if (t == 0) out[0] = 1.f - (sm2[0] + sm2[1]) / ((float)BB * (float)BB);
}

extern "C" void kernel_launch(void* const* d_in, const int* in_sizes, int n_in,
                              void* d_out, int out_size, void* d_ws, size_t ws_size,
                              hipStream_t stream) {
    const float* out_probs = (const float*)d_in[0];
    const int* mask = (const int*)d_in[1];
    float* ws = (float*)d_ws;    // 3*16*8*128 floats = 192 KiB
    float* loss = (float*)d_out;

    dice_partial<<<NBLOCKS, 256, 0, stream>>>(out_probs, mask, ws);
    dice_final<<<1, 1024, 0, stream>>>(ws, loss);
}

// Round 9
// 29.578 us; speedup vs baseline: 6.3697x; 1.0922x over previous
//
#include <hip/hip_runtime.h>

// DICE multi-class loss.
//   output: [B=16, C=8, H=512, W=512] fp32
//   mask:   [B=16, H=512, W=512] int32 (labels 0..7)
// loss = 1 - sum_{b,c} dice(b,c) / (B*B),  dice = 2*(num+eps)/(den1+den2+eps)
//
// Journal:
// R4: 8 waves/CU latency-bound (37us). R5 BEST: NT + DPP reduce, BPB=128,
//     32 waves/CU -> 30.66us. R6: per-block device fences = 6x disaster.
// R8: A/B proved NT loads help (+5%): plain loads 32.3 vs NT 30.7.
// R9: single variable vs R5: BPB 128->64 (1024 blocks, 16 waves/CU, 4 iters).
//     Tests the occupancy midpoint; halves tail events + stage-2 reads.

#define BB 16
#define CC 8
#define HWPIX (512 * 512)
#define HW4 (HWPIX / 4)      // 65536 float4-quads per plane
#define BPB 64               // partial-blocks per batch image
#define QPB (HW4 / BPB)      // 1024 quads per block -> 4 iters/thread
#define NBLOCKS (BB * BPB)   // 1024 blocks = 4/CU, 16 waves/CU

typedef float f32x4 __attribute__((ext_vector_type(4)));
typedef int i32x4 __attribute__((ext_vector_type(4)));

// ---- DPP wave64 sum (VALU pipe only, no DS ops); total lands in lane 63 ----
template <int CTRL>
__device__ __forceinline__ float dpp_add(float x) {
    int yi = __builtin_amdgcn_update_dpp(0, __float_as_int(x), CTRL, 0xf, 0xf, true);
    return x + __int_as_float(yi);
}
__device__ __forceinline__ float wave_sum63(float x) {
    x = dpp_add<0x111>(x);   // row_shr:1
    x = dpp_add<0x112>(x);   // row_shr:2
    x = dpp_add<0x114>(x);   // row_shr:4
    x = dpp_add<0x118>(x);   // row_shr:8
    x = dpp_add<0x142>(x);   // row_bcast:15
    x = dpp_add<0x143>(x);   // row_bcast:31
    return x;
}

__global__ __launch_bounds__(256) void dice_partial(const float* __restrict__ out,
                                                    const int* __restrict__ mask,
                                                    float* __restrict__ ws) {
    const int b = blockIdx.x / BPB;
    const int blk = blockIdx.x % BPB;
    const f32x4* __restrict__ ov = (const f32x4*)(out + (size_t)b * CC * HWPIX);
    const i32x4* __restrict__ mv = (const i32x4*)(mask + (size_t)b * HWPIX);

    float num[CC], d1[CC], d2[CC];
#pragma unroll
    for (int c = 0; c < CC; ++c) { num[c] = 0.f; d1[c] = 0.f; d2[c] = 0.f; }

    const int q0 = blk * QPB;
#pragma unroll 2
    for (int q = q0 + threadIdx.x; q < q0 + QPB; q += 256) {
        const i32x4 m = __builtin_nontemporal_load(&mv[q]);
        f32x4 v[CC];
#pragma unroll
        for (int c = 0; c < CC; ++c) v[c] = __builtin_nontemporal_load(&ov[c * HW4 + q]);
#pragma unroll
        for (int c = 0; c < CC; ++c) {
            d1[c] += v[c].x * v[c].x + v[c].y * v[c].y + v[c].z * v[c].z + v[c].w * v[c].w;
            float hx = (m.x == c) ? 1.f : 0.f;
            float hy = (m.y == c) ? 1.f : 0.f;
            float hz = (m.z == c) ? 1.f : 0.f;
            float hw = (m.w == c) ? 1.f : 0.f;
            num[c] += hx * v[c].x + hy * v[c].y + hz * v[c].z + hw * v[c].w;
            d2[c] += hx + hy + hz + hw;
        }
    }

    const int lane = threadIdx.x & 63;
    const int wid = threadIdx.x >> 6;
    __shared__ float red[4][24];
#pragma unroll
    for (int c = 0; c < CC; ++c) {
        float a0 = wave_sum63(num[c]);
        float a1 = wave_sum63(d1[c]);
        float a2 = wave_sum63(d2[c]);
        if (lane == 63) {
            red[wid][0 * 8 + c] = a0;
            red[wid][1 * 8 + c] = a1;
            red[wid][2 * 8 + c] = a2;
        }
    }
    __syncthreads();
    if (threadIdx.x < 24) {
        const int k = threadIdx.x;       // k = qy*8 + c
        const int qy = k >> 3;
        const int c = k & 7;
        float s = red[0][k] + red[1][k] + red[2][k] + red[3][k];
        // partial layout: ws[((qy*BB + b)*CC + c)*BPB + blk]
        ws[((qy * BB + b) * CC + c) * BPB + blk] = s;
    }
}

// 1024 threads: 8 threads per (b,c) pair, 2 f32x4 loads per quantity.
__global__ __launch_bounds__(1024) void dice_final(const float* __restrict__ ws,
                                                   float* __restrict__ out) {
    const int t = threadIdx.x;
    const int g = t >> 3;        // (b,c) group 0..127
    const int sub = t & 7;
    const int b = g >> 3;
    const int c = g & 7;

    float acc[3] = {0.f, 0.f, 0.f};   // num, d1, d2
#pragma unroll
    for (int qy = 0; qy < 3; ++qy) {
        const f32x4* p = (const f32x4*)(ws + ((qy * BB + b) * CC + c) * BPB);
#pragma unroll
        for (int i = 0; i < BPB / (8 * 4); ++i) {   // 2 f32x4 per thread
            f32x4 v = p[sub + i * 8];
            acc[qy] += v.x + v.y + v.z + v.w;
        }
    }
#pragma unroll
    for (int qy = 0; qy < 3; ++qy) {
#pragma unroll
        for (int o = 4; o > 0; o >>= 1) acc[qy] += __shfl_down(acc[qy], o, 8);
    }

    __shared__ float sm[128];
    __shared__ float sm2[2];
    if (sub == 0) {
        const float eps = 1e-7f;
        sm[g] = 2.f * (acc[0] + eps) / (acc[1] + acc[2] + eps);
    }
    __syncthreads();
    if (t < 128) {
        float x = wave_sum63(sm[t]);
        if ((t & 63) == 63) sm2[t >> 6] = x;
    }
    __syncthreads();
    if (t == 0) out[0] = 1.f - (sm2[0] + sm2[1]) / ((float)BB * (float)BB);
}

extern "C" void kernel_launch(void* const* d_in, const int* in_sizes, int n_in,
                              void* d_out, int out_size, void* d_ws, size_t ws_size,
                              hipStream_t stream) {
    const float* out_probs = (const float*)d_in[0];
    const int* mask = (const int*)d_in[1];
    float* ws = (float*)d_ws;    // 3*16*8*64 floats = 96 KiB
    float* loss = (float*)d_out;

    dice_partial<<<NBLOCKS, 256, 0, stream>>>(out_probs, mask, ws);
    dice_final<<<1, 1024, 0, stream>>>(ws, loss);
}